// Round 5
// baseline (323.843 us; speedup 1.0000x reference)
//
#include <hip/hip_runtime.h>
#include <stdint.h>
#include <math.h>

#define NQ   2562
#define MPTS 16384

// ---------------------------------------------------------------------------
// Kernel 1: copy inputs [N,3] into output columns 0..2 of [N,15]
// ---------------------------------------------------------------------------
__global__ __launch_bounds__(256)
void passthrough_kernel(const float* __restrict__ inp, float* __restrict__ out) {
    int gid = blockIdx.x * 256 + threadIdx.x;
    if (gid < NQ * 3) {
        int n = gid / 3, c = gid - n * 3;
        out[n * 15 + c] = inp[gid];
    }
}

// key = (x^2sum + y^2sum) - 2*x.y   mirroring numpy association (left-assoc _rn,
// fma dot with pre-doubled query coords)
__device__ __forceinline__ float sqsum3(float y0, float y1, float y2) {
    return __fadd_rn(__fadd_rn(__fmul_rn(y0, y0), __fmul_rn(y1, y1)),
                     __fmul_rn(y2, y2));
}
__device__ __forceinline__ float keyf(float xs, float a2, float b2, float c2,
                                      float y0, float y1, float y2, float ysq) {
    float u = fmaf(c2, y2, fmaf(b2, y1, __fmul_rn(a2, y0)));
    return __fsub_rn(__fadd_rn(xs, ysq), u);
}
__device__ __forceinline__ unsigned long long packkey(float k, int m) {
    uint32_t kb = __float_as_uint(k);
    kb ^= (uint32_t)((int32_t)kb >> 31) | 0x80000000u;  // monotonic total-order map
    return ((unsigned long long)kb << 32) | (unsigned)m;
}

// ---------------------------------------------------------------------------
// Kernel 2: block = 4 waves; block b owns queries q = 4b..4b+3 (q = pc*NQ + n).
// Wave wid streams points [wid*4096, (wid+1)*4096). Within a wave, query r's
// chunk-local top-16 lives sorted (ascending packed (key,idx) u64) across lane
// group r (lanes 16r..16r+15), one u64/lane. Epilogue: 4x16 candidates per
// query merged by a 64-lane bitonic sort; lanes 0..15 = global top-16.
// ---------------------------------------------------------------------------
__global__ __launch_bounds__(256)
void knn_kernel(const float* __restrict__ inp,
                const float* __restrict__ pc0, const float* __restrict__ pc1,
                const float* __restrict__ pc2, const float* __restrict__ pc3,
                float* __restrict__ out) {
    const int w    = blockIdx.x;          // 0..2561
    const int wid  = threadIdx.x >> 6;    // wave 0..3
    const int lane = threadIdx.x & 63;
    const int grp  = lane >> 4;           // 16-lane group = query slot
    const int l16  = lane & 15;

    // Per-block 4 queries: coefficients (wave-uniform values)
    float A2[4], B2[4], C2[4], XS[4];
    int   pcid[4];
    const float* Pr[4];
#pragma unroll
    for (int r = 0; r < 4; ++r) {
        int q  = 4 * w + r;
        int pc = q / NQ;
        int n  = q - pc * NQ;
        pcid[r] = pc;
        const float* P = (pc == 0) ? pc0 : (pc == 1) ? pc1 : (pc == 2) ? pc2 : pc3;
        Pr[r] = P;
        float x0 = inp[n * 3 + 0];
        float x1 = inp[n * 3 + 1];
        float x2 = inp[n * 3 + 2];
        A2[r] = 2.0f * x0;
        B2[r] = 2.0f * x1;
        C2[r] = 2.0f * x2;
        XS[r] = sqsum3(x0, x1, x2);
    }
    const bool uni = (pcid[0] == pcid[3]);
    const float* P0 = Pr[0];

    unsigned long long s = ~0ULL;                      // my slot of group's sorted-16
    unsigned long long kth[4]  = {~0ULL, ~0ULL, ~0ULL, ~0ULL};
    float              kthf[4] = {INFINITY, INFINITY, INFINITY, INFINITY};

    // serial wave-wide sorted insert of every ballot'd candidate, with pruning
    auto ins = [&](int r, unsigned long long pk) {
        unsigned long long ball = __ballot(pk < kth[r]);
        while (ball) {
            int src = __ffsll(ball) - 1;
            unsigned long long cand = __shfl(pk, src);
            unsigned long long sp = __shfl_up(s, 1, 16);
            unsigned long long ns;
            if (s < cand)                    ns = s;     // stays
            else if (l16 == 0 || sp < cand)  ns = cand;  // insert here
            else                             ns = sp;    // shifted up
            if (grp == r) s = ns;
            kth[r] = __shfl(s, r * 16 + 15);
            ball &= ball - 1;
            ball &= __ballot(pk < kth[r]);   // prune now-unqualified candidates
        }
        uint32_t kb = (uint32_t)(kth[r] >> 32);
        uint32_t ub = (kb & 0x80000000u) ? (kb ^ 0x80000000u) : ~kb;
        kthf[r] = (kth[r] == ~0ULL) ? INFINITY : __uint_as_float(ub);
    };

    const int mbase = wid << 12;           // wid * 4096

    if (uni) {
#pragma unroll 2
        for (int t = 0; t < 16; ++t) {
            const int mofs = mbase + (t << 8) + (lane << 2);
            float4 px = *(const float4*)(P0 + mofs);
            float4 py = *(const float4*)(P0 + MPTS + mofs);
            float4 pz = *(const float4*)(P0 + 2 * MPTS + mofs);
            float q0 = sqsum3(px.x, py.x, pz.x);
            float q1 = sqsum3(px.y, py.y, pz.y);
            float q2 = sqsum3(px.z, py.z, pz.z);
            float q3 = sqsum3(px.w, py.w, pz.w);
#pragma unroll
            for (int r = 0; r < 4; ++r) {
                float k0 = keyf(XS[r], A2[r], B2[r], C2[r], px.x, py.x, pz.x, q0);
                float k1 = keyf(XS[r], A2[r], B2[r], C2[r], px.y, py.y, pz.y, q1);
                float k2 = keyf(XS[r], A2[r], B2[r], C2[r], px.z, py.z, pz.z, q2);
                float k3 = keyf(XS[r], A2[r], B2[r], C2[r], px.w, py.w, pz.w, q3);
                float kmin = fminf(fminf(k0, k1), fminf(k2, k3));
                if (__ballot(kmin <= kthf[r])) {     // <= : superset incl. key-ties
                    ins(r, packkey(k0, mofs + 0));
                    ins(r, packkey(k1, mofs + 1));
                    ins(r, packkey(k2, mofs + 2));
                    ins(r, packkey(k3, mofs + 3));
                }
            }
        }
    } else {   // boundary blocks (3 of 2562): per-query point stream
        for (int t = 0; t < 16; ++t) {
            const int mofs = mbase + (t << 8) + (lane << 2);
#pragma unroll
            for (int r = 0; r < 4; ++r) {
                const float* P = Pr[r];
                float4 px = *(const float4*)(P + mofs);
                float4 py = *(const float4*)(P + MPTS + mofs);
                float4 pz = *(const float4*)(P + 2 * MPTS + mofs);
                float k0 = keyf(XS[r], A2[r], B2[r], C2[r], px.x, py.x, pz.x,
                                sqsum3(px.x, py.x, pz.x));
                float k1 = keyf(XS[r], A2[r], B2[r], C2[r], px.y, py.y, pz.y,
                                sqsum3(px.y, py.y, pz.y));
                float k2 = keyf(XS[r], A2[r], B2[r], C2[r], px.z, py.z, pz.z,
                                sqsum3(px.z, py.z, pz.z));
                float k3 = keyf(XS[r], A2[r], B2[r], C2[r], px.w, py.w, pz.w,
                                sqsum3(px.w, py.w, pz.w));
                float kmin = fminf(fminf(k0, k1), fminf(k2, k3));
                if (__ballot(kmin <= kthf[r])) {
                    ins(r, packkey(k0, mofs + 0));
                    ins(r, packkey(k1, mofs + 1));
                    ins(r, packkey(k2, mofs + 2));
                    ins(r, packkey(k3, mofs + 3));
                }
            }
        }
    }

    // ---- merge: 4 waves x 16 candidates per query -> global top-16 ----
    __shared__ unsigned long long cbuf[4][4][16];   // [query r][wave][pos]
    cbuf[grp][wid][l16] = s;
    __syncthreads();

    // wave `wid` owns query r = wid: 64 candidates, one per lane
    unsigned long long v = cbuf[wid][grp][l16];

    // 64-lane bitonic sort, ascending (u64 packed order = (d2, idx) order)
#pragma unroll
    for (int k = 2; k <= 64; k <<= 1) {
#pragma unroll
        for (int j = k >> 1; j > 0; j >>= 1) {
            unsigned long long p = __shfl_xor(v, j);
            bool keepmin = (((lane & k) == 0) == ((lane & j) == 0));
            unsigned long long mn = (v < p) ? v : p;
            unsigned long long mx = (v < p) ? p : v;
            v = keepmin ? mn : mx;
        }
    }

    // lanes 0..15 hold the global top-16; gather coords and mean
    if (lane < 16) {
        int q   = 4 * w + wid;
        int pcg = q / NQ;
        int ng  = q - pcg * NQ;
        const float* Pg = (pcg == 0) ? pc0 : (pcg == 1) ? pc1
                        : (pcg == 2) ? pc2 : pc3;
        int idx = (int)(unsigned)v;
        float gx = Pg[idx];
        float gy = Pg[MPTS + idx];
        float gz = Pg[2 * MPTS + idx];
#pragma unroll
        for (int off = 8; off > 0; off >>= 1) {
            gx += __shfl_down(gx, off, 16);
            gy += __shfl_down(gy, off, 16);
            gz += __shfl_down(gz, off, 16);
        }
        if (lane == 0) {
            float* o = out + ng * 15 + 3 + 3 * pcg;
            o[0] = gx * 0.0625f;
            o[1] = gy * 0.0625f;
            o[2] = gz * 0.0625f;
        }
    }
}

extern "C" void kernel_launch(void* const* d_in, const int* in_sizes, int n_in,
                              void* d_out, int out_size, void* d_ws, size_t ws_size,
                              hipStream_t stream) {
    const float* inp = (const float*)d_in[0];
    const float* pc0 = (const float*)d_in[1];
    const float* pc1 = (const float*)d_in[2];
    const float* pc2 = (const float*)d_in[3];
    const float* pc3 = (const float*)d_in[4];
    float* out = (float*)d_out;

    hipLaunchKernelGGL(passthrough_kernel, dim3((NQ * 3 + 255) / 256), dim3(256),
                       0, stream, inp, out);

    // 4 pcs * 2562 queries = 10248 query-instances; 4 queries per block,
    // 4 waves per block each covering 4096 of the 16384 points
    hipLaunchKernelGGL(knn_kernel, dim3(2562), dim3(256), 0, stream,
                       inp, pc0, pc1, pc2, pc3, out);
}

// Round 6
// 200.279 us; speedup vs baseline: 1.6170x; 1.6170x over previous
//
#include <hip/hip_runtime.h>
#include <stdint.h>
#include <math.h>

#define NQ    2562
#define MPTS  16384
#define NBQ   641          // blocks per point cloud (ceil(2562/4))
#define CAP   320          // stack capacity per (wave, query): 64 trigger + 256 worst-case one-iter push

// ---------------------------------------------------------------------------
// Kernel 1: copy inputs [N,3] into output columns 0..2 of [N,15]
// ---------------------------------------------------------------------------
__global__ __launch_bounds__(256)
void passthrough_kernel(const float* __restrict__ inp, float* __restrict__ out) {
    int gid = blockIdx.x * 256 + threadIdx.x;
    if (gid < NQ * 3) {
        int n = gid / 3, c = gid - n * 3;
        out[n * 15 + c] = inp[gid];
    }
}

// key = (x^2sum + y^2sum) - 2*x.y  mirroring numpy association (left-assoc _rn,
// fma dot with pre-doubled query coords). Identical formula used in streaming
// and rebuild-recompute -> bitwise-identical keys.
__device__ __forceinline__ float sqsum3(float y0, float y1, float y2) {
    return __fadd_rn(__fadd_rn(__fmul_rn(y0, y0), __fmul_rn(y1, y1)),
                     __fmul_rn(y2, y2));
}
__device__ __forceinline__ float keyf(float xs, float a2, float b2, float c2,
                                      float y0, float y1, float y2, float ysq) {
    float u = fmaf(c2, y2, fmaf(b2, y1, __fmul_rn(a2, y0)));
    return __fsub_rn(__fadd_rn(xs, ysq), u);
}
__device__ __forceinline__ unsigned long long packkey(float k, int m) {
    uint32_t kb = __float_as_uint(k);
    kb ^= (uint32_t)((int32_t)kb >> 31) | 0x80000000u;  // monotonic total-order map
    return ((unsigned long long)kb << 32) | (unsigned)m;
}
__device__ __forceinline__ float unmapkey(unsigned long long pk) {
    uint32_t kb = (uint32_t)(pk >> 32);
    return __uint_as_float((kb & 0x80000000u) ? (kb ^ 0x80000000u) : ~kb);
}

// 64-lane bitonic sort ascending; lane l ends with the l-th smallest value.
__device__ __forceinline__ unsigned long long sort64(unsigned long long v, int lane) {
#pragma unroll
    for (int k = 2; k <= 64; k <<= 1) {
#pragma unroll
        for (int j = k >> 1; j > 0; j >>= 1) {
            unsigned long long p = __shfl_xor(v, j);
            bool up = ((lane & k) == 0) == ((lane & j) == 0);
            bool sw = up ? (p < v) : (v < p);
            v = sw ? p : v;
        }
    }
    return v;
}

// Wave-collective: fold stack (u32 point indices, keys recomputed) into the
// sorted top-16 held in t16[0..15] (LDS, packed u64). Returns new tau =
// exact 16th-smallest key so far. Call only with cnt>0 and full wave active.
__device__ __forceinline__ float rebuild_q(unsigned long long* t16,
                                           const unsigned* stk, int* cntp,
                                           int lane, const float* __restrict__ P,
                                           float xs, float a2, float b2, float c2) {
    int c = *cntp;                       // wave-uniform LDS broadcast
    unsigned long long v = ~0ULL;
    for (int base = 0; base < c; base += 48) {
        if (lane < 16) {
            v = t16[lane];
        } else {
            int i = base + lane - 16;
            v = ~0ULL;
            if (i < c) {
                int idx = (int)stk[i];
                float y0 = P[idx], y1 = P[MPTS + idx], y2 = P[2 * MPTS + idx];
                float key = keyf(xs, a2, b2, c2, y0, y1, y2, sqsum3(y0, y1, y2));
                v = packkey(key, idx);
            }
        }
        v = sort64(v, lane);
        if (lane < 16) t16[lane] = v;
    }
    if (lane == 0) *cntp = 0;
    unsigned long long kv = __shfl(v, 15);
    return unmapkey(kv);
}

// ---------------------------------------------------------------------------
// Kernel 2: grid 4*NBQ blocks x 256 threads. Block b: pc = b/NBQ (uniform),
// queries n_r = min(4*(b%NBQ)+r, NQ-1), r=0..3. Wave wid streams points
// [wid*4096, (wid+1)*4096). Selection: f32 threshold tau + LDS index stack,
// batched exact rebuilds via 64-lane bitonic sort on packed (key,idx).
// ---------------------------------------------------------------------------
__global__ __launch_bounds__(256)
void knn_kernel(const float* __restrict__ inp,
                const float* __restrict__ pc0, const float* __restrict__ pc1,
                const float* __restrict__ pc2, const float* __restrict__ pc3,
                float* __restrict__ out) {
    const int b    = blockIdx.x;          // 0..4*NBQ-1
    const int wid  = threadIdx.x >> 6;    // wave 0..3
    const int lane = threadIdx.x & 63;

    const int pc = b / NBQ;
    const int nb = b - pc * NBQ;
    const float* __restrict__ P = (pc == 0) ? pc0 : (pc == 1) ? pc1
                                : (pc == 2) ? pc2 : pc3;

    __shared__ unsigned           stk_sh[4][4][CAP];   // [wave][query][pos] point idx
    __shared__ int                cnt_sh[4][4];
    __shared__ unsigned long long t16_sh[4][4][16];    // [wave][query][slot] packed

    if (lane < 4) cnt_sh[wid][lane] = 0;
    t16_sh[wid][lane >> 4][lane & 15] = ~0ULL;
    // no __syncthreads needed: each wave touches only its [wid] row until the tail

    // query coefficients (block-uniform per r)
    float A2[4], B2[4], C2[4], XS[4];
#pragma unroll
    for (int r = 0; r < 4; ++r) {
        int n = 4 * nb + r;
        n = (n < NQ) ? n : (NQ - 1);      // tail blocks: duplicate last query (benign)
        float x0 = inp[n * 3 + 0];
        float x1 = inp[n * 3 + 1];
        float x2 = inp[n * 3 + 2];
        A2[r] = 2.0f * x0;
        B2[r] = 2.0f * x1;
        C2[r] = 2.0f * x2;
        XS[r] = sqsum3(x0, x1, x2);
    }
    float tau[4] = {INFINITY, INFINITY, INFINITY, INFINITY};

    const int mbase = wid << 12;          // wid * 4096

    for (int t = 0; t < 16; ++t) {
        const int mofs = mbase + (t << 8) + (lane << 2);
        float4 px = *(const float4*)(P + mofs);
        float4 py = *(const float4*)(P + MPTS + mofs);
        float4 pz = *(const float4*)(P + 2 * MPTS + mofs);
        float q0 = sqsum3(px.x, py.x, pz.x);
        float q1 = sqsum3(px.y, py.y, pz.y);
        float q2 = sqsum3(px.z, py.z, pz.z);
        float q3 = sqsum3(px.w, py.w, pz.w);
#pragma unroll
        for (int r = 0; r < 4; ++r) {
            float k0 = keyf(XS[r], A2[r], B2[r], C2[r], px.x, py.x, pz.x, q0);
            float k1 = keyf(XS[r], A2[r], B2[r], C2[r], px.y, py.y, pz.y, q1);
            float k2 = keyf(XS[r], A2[r], B2[r], C2[r], px.z, py.z, pz.z, q2);
            float k3 = keyf(XS[r], A2[r], B2[r], C2[r], px.w, py.w, pz.w, q3);

            if (t == 0) {
                // warm start: tau0 = 16th-smallest lane-min (upper bound on the
                // true 16th of these 256 points: >=16 points have key <= tau0)
                float kmn = k0; int im = mofs;
                if (k1 < kmn) { kmn = k1; im = mofs + 1; }
                if (k2 < kmn) { kmn = k2; im = mofs + 2; }
                if (k3 < kmn) { kmn = k3; im = mofs + 3; }
                unsigned long long sv = sort64(packkey(kmn, im), lane);
                tau[r] = unmapkey(__shfl(sv, 15));
            }

            float kmin = fminf(fminf(k0, k1), fminf(k2, k3));
            if (__ballot(kmin <= tau[r])) {           // wave-uniform gate
                unsigned msk = (k0 <= tau[r] ? 1u : 0u) | (k1 <= tau[r] ? 2u : 0u)
                             | (k2 <= tau[r] ? 4u : 0u) | (k3 <= tau[r] ? 8u : 0u);
                int np = __popc(msk);
                int pos = 0;
                if (np) pos = atomicAdd(&cnt_sh[wid][r], np);
                unsigned* S = stk_sh[wid][r];
                if (msk & 1u) S[pos++] = (unsigned)(mofs + 0);
                if (msk & 2u) S[pos++] = (unsigned)(mofs + 1);
                if (msk & 4u) S[pos++] = (unsigned)(mofs + 2);
                if (msk & 8u) S[pos++] = (unsigned)(mofs + 3);
                // trigger: keep headroom for next iter's worst-case 256 pushes
                if (cnt_sh[wid][r] >= 64)
                    tau[r] = rebuild_q(t16_sh[wid][r], S, &cnt_sh[wid][r], lane,
                                       P, XS[r], A2[r], B2[r], C2[r]);
            }
        }
    }

    // final fold of remaining stack entries
#pragma unroll
    for (int r = 0; r < 4; ++r) {
        if (cnt_sh[wid][r] > 0)
            rebuild_q(t16_sh[wid][r], stk_sh[wid][r], &cnt_sh[wid][r], lane,
                      P, XS[r], A2[r], B2[r], C2[r]);
    }
    __syncthreads();

    // tail: wave wid owns query slot r=wid; merge 4 waves x 16 candidates
    unsigned long long v = t16_sh[lane >> 4][wid][lane & 15];
    v = sort64(v, lane);                 // lanes 0..15 = global top-16 (key, idx asc)

    if (lane < 16) {
        int idx = (int)(unsigned)v;
        float gx = P[idx];
        float gy = P[MPTS + idx];
        float gz = P[2 * MPTS + idx];
#pragma unroll
        for (int off = 8; off > 0; off >>= 1) {
            gx += __shfl_down(gx, off, 16);
            gy += __shfl_down(gy, off, 16);
            gz += __shfl_down(gz, off, 16);
        }
        if (lane == 0) {
            int n = 4 * nb + wid;
            n = (n < NQ) ? n : (NQ - 1);  // duplicate writes carry identical values
            float* o = out + n * 15 + 3 + 3 * pc;
            o[0] = gx * 0.0625f;
            o[1] = gy * 0.0625f;
            o[2] = gz * 0.0625f;
        }
    }
}

extern "C" void kernel_launch(void* const* d_in, const int* in_sizes, int n_in,
                              void* d_out, int out_size, void* d_ws, size_t ws_size,
                              hipStream_t stream) {
    const float* inp = (const float*)d_in[0];
    const float* pc0 = (const float*)d_in[1];
    const float* pc1 = (const float*)d_in[2];
    const float* pc2 = (const float*)d_in[3];
    const float* pc3 = (const float*)d_in[4];
    float* out = (float*)d_out;

    hipLaunchKernelGGL(passthrough_kernel, dim3((NQ * 3 + 255) / 256), dim3(256),
                       0, stream, inp, out);

    // 4 pcs x 641 blocks; each block: one pc, 4 queries, 4 waves x 4096 points
    hipLaunchKernelGGL(knn_kernel, dim3(4 * NBQ), dim3(256), 0, stream,
                       inp, pc0, pc1, pc2, pc3, out);
}

// Round 7
// 154.408 us; speedup vs baseline: 2.0973x; 1.2971x over previous
//
#include <hip/hip_runtime.h>
#include <stdint.h>
#include <math.h>

#define NQ    2562
#define MPTS  16384
#define QPB   8            // queries per block
#define NBQ   321          // ceil(NQ / QPB) blocks per point cloud
#define HALF  8192         // points per wave (M split across 2 waves)
#define CAP   320          // stack cap per (wave,query): 63 leftover + 256 worst-case iter

// ---------------------------------------------------------------------------
// Kernel 1: copy inputs [N,3] into output columns 0..2 of [N,15]
// ---------------------------------------------------------------------------
__global__ __launch_bounds__(256)
void passthrough_kernel(const float* __restrict__ inp, float* __restrict__ out) {
    int gid = blockIdx.x * 256 + threadIdx.x;
    if (gid < NQ * 3) {
        int n = gid / 3, c = gid - n * 3;
        out[n * 15 + c] = inp[gid];
    }
}

// key = (x^2sum + y^2sum) - 2*x.y  mirroring numpy association (left-assoc _rn,
// fma dot with pre-doubled query coords). Same formula in stream and rebuild
// -> bitwise-identical keys.
__device__ __forceinline__ float sqsum3(float y0, float y1, float y2) {
    return __fadd_rn(__fadd_rn(__fmul_rn(y0, y0), __fmul_rn(y1, y1)),
                     __fmul_rn(y2, y2));
}
__device__ __forceinline__ float keyf(float xs, float a2, float b2, float c2,
                                      float y0, float y1, float y2, float ysq) {
    float u = fmaf(c2, y2, fmaf(b2, y1, __fmul_rn(a2, y0)));
    return __fsub_rn(__fadd_rn(xs, ysq), u);
}
__device__ __forceinline__ unsigned long long packkey(float k, int m) {
    uint32_t kb = __float_as_uint(k);
    kb ^= (uint32_t)((int32_t)kb >> 31) | 0x80000000u;  // monotonic total-order map
    return ((unsigned long long)kb << 32) | (unsigned)m;
}
__device__ __forceinline__ float unmapkey(unsigned long long pk) {
    uint32_t kb = (uint32_t)(pk >> 32);
    return __uint_as_float((kb & 0x80000000u) ? (kb ^ 0x80000000u) : ~kb);
}

// 64-lane bitonic sort ascending; lane l ends with the l-th smallest value.
__device__ __forceinline__ unsigned long long sort64(unsigned long long v, int lane) {
#pragma unroll
    for (int k = 2; k <= 64; k <<= 1) {
#pragma unroll
        for (int j = k >> 1; j > 0; j >>= 1) {
            unsigned long long p = __shfl_xor(v, j);
            bool up = ((lane & k) == 0) == ((lane & j) == 0);
            bool sw = up ? (p < v) : (v < p);
            v = sw ? p : v;
        }
    }
    return v;
}

// Wave-collective: fold stack chunks into sorted t16 (LDS). Mid-stream
// (fin=false): process only full 64-chunks, compact remainder (tau from the
// folded t16 stays a valid upper bound of the running true 16th since the
// remainder is still in the candidate stack). Final (fin=true): process all.
// Returns new tau = key of t16[15].
__device__ __forceinline__ float rebuild_q(unsigned long long* t16p,
                                           unsigned* S, int* cntp, int lane,
                                           const float* __restrict__ P,
                                           float xs, float a2, float b2, float c2,
                                           bool fin) {
    int c = *cntp;                         // wave-uniform
    int full = c >> 6, rem = c & 63;
    int rounds = full + ((fin && rem) ? 1 : 0);
    unsigned long long v = ~0ULL;
    for (int rd = 0; rd < rounds; ++rd) {
        int i = (rd << 6) + lane;
        unsigned idx = (i < c) ? S[i] : 0u;
        float y0 = P[idx], y1 = P[MPTS + idx], y2 = P[2 * MPTS + idx];
        float key = keyf(xs, a2, b2, c2, y0, y1, y2, sqsum3(y0, y1, y2));
        unsigned long long pk = (i < c) ? packkey(key, (int)idx) : ~0ULL;
        pk = sort64(pk, lane);             // asc across lanes
        // bitonic merge: A = t16 asc (lanes 0-15), B = chunk's smallest-16 desc
        unsigned long long bsw = __shfl(pk, (31 - lane) & 63);
        v = (lane < 16) ? t16p[lane & 15] : (lane < 32) ? bsw : ~0ULL;
#pragma unroll
        for (int j = 16; j > 0; j >>= 1) {
            unsigned long long p2 = __shfl_xor(v, j);
            bool keepmin = (lane & j) == 0;
            bool less = p2 < v;
            v = (keepmin == less) ? p2 : v;
        }
        if (lane < 16) t16p[lane] = v;
    }
    if (!fin) {
        if (lane < rem) S[lane] = S[(full << 6) + lane];   // disjoint ranges (full>=1)
        if (lane == 0) *cntp = rem;
    } else {
        if (lane == 0) *cntp = 0;
    }
    return unmapkey(__shfl(v, 15));
}

// ---------------------------------------------------------------------------
// Kernel 2: grid 4*NBQ x 256. Block b: pc = b/NBQ, base query 8*(b%NBQ).
// Wave pair (wid>>1) owns queries 4*pair..4*pair+3; wave half (wid&1) streams
// points [half*8192, half*8192+8192). Selection: f32 tau gate + LDS index
// stack + batched exact folds (sort64 + bitonic merge) into sorted t16.
// ---------------------------------------------------------------------------
__global__ __launch_bounds__(256)
void knn_kernel(const float* __restrict__ inp,
                const float* __restrict__ pc0, const float* __restrict__ pc1,
                const float* __restrict__ pc2, const float* __restrict__ pc3,
                float* __restrict__ out) {
    const int b    = blockIdx.x;
    const int wid  = threadIdx.x >> 6;
    const int lane = threadIdx.x & 63;
    const int pair = wid >> 1;
    const int half = wid & 1;

    const int pc = b / NBQ;
    const int nb = b - pc * NBQ;
    const float* __restrict__ P = (pc == 0) ? pc0 : (pc == 1) ? pc1
                                : (pc == 2) ? pc2 : pc3;

    __shared__ unsigned           stk_sh[4][4][CAP];
    __shared__ int                cnt_sh[4][4];
    __shared__ unsigned long long t16_sh[4][4][16];

    if (lane < 4) cnt_sh[wid][lane] = 0;
    t16_sh[wid][lane >> 4][lane & 15] = ~0ULL;

    // coefficients for this wave's 4 queries
    float A2[4], B2[4], C2[4], XS[4];
#pragma unroll
    for (int r = 0; r < 4; ++r) {
        int n = QPB * nb + 4 * pair + r;
        n = (n < NQ) ? n : (NQ - 1);       // tail clamp (duplicate-identical work)
        float x0 = inp[n * 3 + 0];
        float x1 = inp[n * 3 + 1];
        float x2 = inp[n * 3 + 2];
        A2[r] = 2.0f * x0;
        B2[r] = 2.0f * x1;
        C2[r] = 2.0f * x2;
        XS[r] = sqsum3(x0, x1, x2);
    }
    float tau[4];

    const int mbase = half * HALF;

    for (int t = 0; t < HALF / 256; ++t) {
        const int mofs = mbase + (t << 8) + (lane << 2);
        float4 px = *(const float4*)(P + mofs);
        float4 py = *(const float4*)(P + MPTS + mofs);
        float4 pz = *(const float4*)(P + 2 * MPTS + mofs);
        float q0 = sqsum3(px.x, py.x, pz.x);
        float q1 = sqsum3(px.y, py.y, pz.y);
        float q2 = sqsum3(px.z, py.z, pz.z);
        float q3 = sqsum3(px.w, py.w, pz.w);
#pragma unroll
        for (int r = 0; r < 4; ++r) {
            float k0 = keyf(XS[r], A2[r], B2[r], C2[r], px.x, py.x, pz.x, q0);
            float k1 = keyf(XS[r], A2[r], B2[r], C2[r], px.y, py.y, pz.y, q1);
            float k2 = keyf(XS[r], A2[r], B2[r], C2[r], px.z, py.z, pz.z, q2);
            float k3 = keyf(XS[r], A2[r], B2[r], C2[r], px.w, py.w, pz.w, q3);
            float kmin = fminf(fminf(k0, k1), fminf(k2, k3));

            if (t == 0) {
                // warm tau0: max over 16 groups (of 4 lanes) of group-mins.
                // Each group-min is one point's key <= tau0 -> >=16 points
                // <= tau0 -> tau0 >= true 16th of these 256. Cheap and valid.
                float g = kmin;
                g = fminf(g, __shfl_xor(g, 1));
                g = fminf(g, __shfl_xor(g, 2));
                float m = g;
                m = fmaxf(m, __shfl_xor(m, 4));
                m = fmaxf(m, __shfl_xor(m, 8));
                m = fmaxf(m, __shfl_xor(m, 16));
                m = fmaxf(m, __shfl_xor(m, 32));
                tau[r] = m;
            }

            if (__ballot(kmin <= tau[r])) {
                unsigned msk = (k0 <= tau[r] ? 1u : 0u) | (k1 <= tau[r] ? 2u : 0u)
                             | (k2 <= tau[r] ? 4u : 0u) | (k3 <= tau[r] ? 8u : 0u);
                int np = __popc(msk);
                int pos = 0;
                if (np) pos = atomicAdd(&cnt_sh[wid][r], np);
                unsigned* S = stk_sh[wid][r];
                if (msk & 1u) S[pos++] = (unsigned)(mofs + 0);
                if (msk & 2u) S[pos++] = (unsigned)(mofs + 1);
                if (msk & 4u) S[pos++] = (unsigned)(mofs + 2);
                if (msk & 8u) S[pos++] = (unsigned)(mofs + 3);
                if (cnt_sh[wid][r] >= 64)      // headroom: 63 + 256 <= CAP-1
                    tau[r] = rebuild_q(t16_sh[wid][r], S, &cnt_sh[wid][r], lane,
                                       P, XS[r], A2[r], B2[r], C2[r], false);
            }
        }
    }

    // final fold of remaining stack entries
#pragma unroll
    for (int r = 0; r < 4; ++r) {
        if (cnt_sh[wid][r] > 0)
            rebuild_q(t16_sh[wid][r], stk_sh[wid][r], &cnt_sh[wid][r], lane,
                      P, XS[r], A2[r], B2[r], C2[r], true);
    }
    __syncthreads();

    // tail: wave wid merges queries {2*wid, 2*wid+1}; 32-lane half h handles
    // query qq = 2*wid + h, merging the two waves' sorted t16s (bitonic merge).
    {
        const int h   = lane >> 5;
        const int l32 = lane & 31;
        const int qq  = 2 * wid + h;       // 0..7 within block
        const int p   = qq >> 2;           // wave pair
        const int r   = qq & 3;
        unsigned long long v =
            (l32 < 16) ? t16_sh[2 * p][r][l32 & 15]
                       : t16_sh[2 * p + 1][r][(31 - l32) & 15];   // B descending
#pragma unroll
        for (int j = 16; j > 0; j >>= 1) {
            unsigned long long p2 = __shfl_xor(v, j);
            bool keepmin = (l32 & j) == 0;
            bool less = p2 < v;
            v = (keepmin == less) ? p2 : v;
        }
        if (l32 < 16) {
            int idx = (int)(unsigned)v;
            float gx = P[idx];
            float gy = P[MPTS + idx];
            float gz = P[2 * MPTS + idx];
#pragma unroll
            for (int off = 8; off > 0; off >>= 1) {
                gx += __shfl_down(gx, off, 16);
                gy += __shfl_down(gy, off, 16);
                gz += __shfl_down(gz, off, 16);
            }
            if (l32 == 0) {
                int n = QPB * nb + qq;
                n = (n < NQ) ? n : (NQ - 1);  // duplicate writes identical
                float* o = out + n * 15 + 3 + 3 * pc;
                o[0] = gx * 0.0625f;
                o[1] = gy * 0.0625f;
                o[2] = gz * 0.0625f;
            }
        }
    }
}

extern "C" void kernel_launch(void* const* d_in, const int* in_sizes, int n_in,
                              void* d_out, int out_size, void* d_ws, size_t ws_size,
                              hipStream_t stream) {
    const float* inp = (const float*)d_in[0];
    const float* pc0 = (const float*)d_in[1];
    const float* pc1 = (const float*)d_in[2];
    const float* pc2 = (const float*)d_in[3];
    const float* pc3 = (const float*)d_in[4];
    float* out = (float*)d_out;

    hipLaunchKernelGGL(passthrough_kernel, dim3((NQ * 3 + 255) / 256), dim3(256),
                       0, stream, inp, out);

    // 4 pcs x 321 blocks; block = 8 queries, 2 wave-pairs x (2 waves x 8192 pts)
    hipLaunchKernelGGL(knn_kernel, dim3(4 * NBQ), dim3(256), 0, stream,
                       inp, pc0, pc1, pc2, pc3, out);
}

// Round 8
// 139.836 us; speedup vs baseline: 2.3159x; 1.1042x over previous
//
#include <hip/hip_runtime.h>
#include <stdint.h>
#include <math.h>

#define NQ    2562
#define MPTS  16384
#define QPB   8            // queries per block
#define NBQ   321          // ceil(NQ / QPB) blocks per point cloud
#define HALF  8192         // points per wave (M split across 2 waves)
#define NT    (HALF / 256) // 32 stream iters per wave
#define CAP   320          // stack cap per (wave,query): 63 leftover + 256 worst-case iter

// ---------------------------------------------------------------------------
// Kernel 1: copy inputs [N,3] into output columns 0..2 of [N,15]
// ---------------------------------------------------------------------------
__global__ __launch_bounds__(256)
void passthrough_kernel(const float* __restrict__ inp, float* __restrict__ out) {
    int gid = blockIdx.x * 256 + threadIdx.x;
    if (gid < NQ * 3) {
        int n = gid / 3, c = gid - n * 3;
        out[n * 15 + c] = inp[gid];
    }
}

// key = (x^2sum + y^2sum) - 2*x.y  mirroring numpy association (left-assoc _rn,
// fma dot with pre-doubled query coords). Same formula in stream and rebuild
// -> bitwise-identical keys.
__device__ __forceinline__ float sqsum3(float y0, float y1, float y2) {
    return __fadd_rn(__fadd_rn(__fmul_rn(y0, y0), __fmul_rn(y1, y1)),
                     __fmul_rn(y2, y2));
}
__device__ __forceinline__ float keyf(float xs, float a2, float b2, float c2,
                                      float y0, float y1, float y2, float ysq) {
    float u = fmaf(c2, y2, fmaf(b2, y1, __fmul_rn(a2, y0)));
    return __fsub_rn(__fadd_rn(xs, ysq), u);
}
__device__ __forceinline__ unsigned long long packkey(float k, int m) {
    uint32_t kb = __float_as_uint(k);
    kb ^= (uint32_t)((int32_t)kb >> 31) | 0x80000000u;  // monotonic total-order map
    return ((unsigned long long)kb << 32) | (unsigned)m;
}
__device__ __forceinline__ float unmapkey(unsigned long long pk) {
    uint32_t kb = (uint32_t)(pk >> 32);
    return __uint_as_float((kb & 0x80000000u) ? (kb ^ 0x80000000u) : ~kb);
}
// popcount of mask over lanes < this lane (v_mbcnt pair)
__device__ __forceinline__ int prefix_lt(unsigned long long m) {
    return __builtin_amdgcn_mbcnt_hi((unsigned)(m >> 32),
           __builtin_amdgcn_mbcnt_lo((unsigned)m, 0u));
}

// 64-lane bitonic sort ascending; lane l ends with the l-th smallest value.
__device__ __forceinline__ unsigned long long sort64(unsigned long long v, int lane) {
#pragma unroll
    for (int k = 2; k <= 64; k <<= 1) {
#pragma unroll
        for (int j = k >> 1; j > 0; j >>= 1) {
            unsigned long long p = __shfl_xor(v, j);
            bool up = ((lane & k) == 0) == ((lane & j) == 0);
            bool sw = up ? (p < v) : (v < p);
            v = sw ? p : v;
        }
    }
    return v;
}

// Wave-collective: fold stack chunks into sorted t16 (LDS). Mid-stream
// (fin=false): process only full 64-chunks, compact remainder. Final
// (fin=true): process all. cnt is wave-uniform (register). Returns new tau.
__device__ __forceinline__ float rebuild_q(unsigned long long* t16p,
                                           unsigned* S, int& cnt, int lane,
                                           const float* __restrict__ P,
                                           float xs, float a2, float b2, float c2,
                                           bool fin) {
    int c = cnt;
    int full = c >> 6, rem = c & 63;
    int rounds = full + ((fin && rem) ? 1 : 0);
    unsigned long long v = ~0ULL;
    for (int rd = 0; rd < rounds; ++rd) {
        int i = (rd << 6) + lane;
        unsigned idx = (i < c) ? S[i] : 0u;
        float y0 = P[idx], y1 = P[MPTS + idx], y2 = P[2 * MPTS + idx];
        float key = keyf(xs, a2, b2, c2, y0, y1, y2, sqsum3(y0, y1, y2));
        unsigned long long pk = (i < c) ? packkey(key, (int)idx) : ~0ULL;
        pk = sort64(pk, lane);             // asc across lanes
        // bitonic merge: A = t16 asc (lanes 0-15), B = chunk's smallest-16 desc
        unsigned long long bsw = __shfl(pk, (31 - lane) & 63);
        v = (lane < 16) ? t16p[lane & 15] : (lane < 32) ? bsw : ~0ULL;
#pragma unroll
        for (int j = 16; j > 0; j >>= 1) {
            unsigned long long p2 = __shfl_xor(v, j);
            bool keepmin = (lane & j) == 0;
            bool less = p2 < v;
            v = (keepmin == less) ? p2 : v;
        }
        if (lane < 16) t16p[lane] = v;
    }
    if (!fin) {
        if (lane < rem) S[lane] = S[(full << 6) + lane];   // disjoint (full>=1)
        cnt = rem;
    } else {
        cnt = 0;
    }
    return unmapkey(__shfl(v, 15));
}

// ---------------------------------------------------------------------------
// Kernel 2: grid 4*NBQ x 256. Block b: pc = b/NBQ, base query 8*(b%NBQ).
// Wave pair (wid>>1) owns queries 4*pair..4*pair+3; wave half (wid&1) streams
// points [half*8192, half*8192+8192). Selection: f32 tau gate + LDS index
// stack (offsets via ballot prefix-sum, counter in SGPR) + batched exact
// folds (sort64 + bitonic merge) into sorted t16.
// ---------------------------------------------------------------------------
__global__ __launch_bounds__(256)
void knn_kernel(const float* __restrict__ inp,
                const float* __restrict__ pc0, const float* __restrict__ pc1,
                const float* __restrict__ pc2, const float* __restrict__ pc3,
                float* __restrict__ out) {
    const int b    = blockIdx.x;
    const int wid  = threadIdx.x >> 6;
    const int lane = threadIdx.x & 63;
    const int pair = wid >> 1;
    const int half = wid & 1;

    const int pc = b / NBQ;
    const int nb = b - pc * NBQ;
    const float* __restrict__ P = (pc == 0) ? pc0 : (pc == 1) ? pc1
                                : (pc == 2) ? pc2 : pc3;

    __shared__ unsigned           stk_sh[4][4][CAP];
    __shared__ unsigned long long t16_sh[4][4][16];

    t16_sh[wid][lane >> 4][lane & 15] = ~0ULL;

    // coefficients for this wave's 4 queries
    float A2[4], B2[4], C2[4], XS[4];
#pragma unroll
    for (int r = 0; r < 4; ++r) {
        int n = QPB * nb + 4 * pair + r;
        n = (n < NQ) ? n : (NQ - 1);       // tail clamp (duplicate-identical work)
        float x0 = inp[n * 3 + 0];
        float x1 = inp[n * 3 + 1];
        float x2 = inp[n * 3 + 2];
        A2[r] = 2.0f * x0;
        B2[r] = 2.0f * x1;
        C2[r] = 2.0f * x2;
        XS[r] = sqsum3(x0, x1, x2);
    }
    float tau[4];
    int   cnt[4] = {0, 0, 0, 0};           // wave-uniform -> SGPR

    const float* __restrict__ Pl = P + half * HALF + (lane << 2);

    // prefetch t=0
    float4 cx = *(const float4*)(Pl);
    float4 cy = *(const float4*)(Pl + MPTS);
    float4 cz = *(const float4*)(Pl + 2 * MPTS);

    for (int t = 0; t < NT; ++t) {
        // prefetch t+1 (wraps to t=0 on last iter; harmless L2 re-hit)
        const int tn = (t + 1) & (NT - 1);
        float4 nx = *(const float4*)(Pl + (tn << 8));
        float4 ny = *(const float4*)(Pl + MPTS + (tn << 8));
        float4 nz = *(const float4*)(Pl + 2 * MPTS + (tn << 8));

        const int mofs = half * HALF + (t << 8) + (lane << 2);
        float q0 = sqsum3(cx.x, cy.x, cz.x);
        float q1 = sqsum3(cx.y, cy.y, cz.y);
        float q2 = sqsum3(cx.z, cy.z, cz.z);
        float q3 = sqsum3(cx.w, cy.w, cz.w);

        float k0[4], k1[4], k2[4], k3[4], km[4];
#pragma unroll
        for (int r = 0; r < 4; ++r) {
            k0[r] = keyf(XS[r], A2[r], B2[r], C2[r], cx.x, cy.x, cz.x, q0);
            k1[r] = keyf(XS[r], A2[r], B2[r], C2[r], cx.y, cy.y, cz.y, q1);
            k2[r] = keyf(XS[r], A2[r], B2[r], C2[r], cx.z, cy.z, cz.z, q2);
            k3[r] = keyf(XS[r], A2[r], B2[r], C2[r], cx.w, cy.w, cz.w, q3);
            km[r] = fminf(fminf(k0[r], k1[r]), fminf(k2[r], k3[r]));
        }

        if (t == 0) {
            // warm tau0[r]: max over 16 groups (of 4 lanes) of group-mins;
            // >=16 distinct points <= tau0 -> tau0 >= true 16th of these 256.
#pragma unroll
            for (int r = 0; r < 4; ++r) {
                float g = km[r];
                g = fminf(g, __shfl_xor(g, 1));
                g = fminf(g, __shfl_xor(g, 2));
                float m = g;
                m = fmaxf(m, __shfl_xor(m, 4));
                m = fmaxf(m, __shfl_xor(m, 8));
                m = fmaxf(m, __shfl_xor(m, 16));
                m = fmaxf(m, __shfl_xor(m, 32));
                tau[r] = m;
            }
        }

#pragma unroll
        for (int r = 0; r < 4; ++r) {
            if (__ballot(km[r] <= tau[r])) {
                // per-point qualify masks -> ballot bit-planes -> prefix offsets
                unsigned long long b0 = __ballot(k0[r] <= tau[r]);
                unsigned long long b1 = __ballot(k1[r] <= tau[r]);
                unsigned long long b2 = __ballot(k2[r] <= tau[r]);
                unsigned long long b3 = __ballot(k3[r] <= tau[r]);
                int pre = prefix_lt(b0) + prefix_lt(b1) + prefix_lt(b2) + prefix_lt(b3);
                int tot = __popcll(b0) + __popcll(b1) + __popcll(b2) + __popcll(b3);
                int pos = cnt[r] + pre;
                unsigned* S = stk_sh[wid][r];
                if (k0[r] <= tau[r]) S[pos++] = (unsigned)(mofs + 0);
                if (k1[r] <= tau[r]) S[pos++] = (unsigned)(mofs + 1);
                if (k2[r] <= tau[r]) S[pos++] = (unsigned)(mofs + 2);
                if (k3[r] <= tau[r]) S[pos++] = (unsigned)(mofs + 3);
                cnt[r] += tot;                     // uniform update
                if (cnt[r] >= 64)                  // headroom: 63 + 256 <= CAP-1
                    tau[r] = rebuild_q(t16_sh[wid][r], S, cnt[r], lane,
                                       P, XS[r], A2[r], B2[r], C2[r], false);
            }
        }

        cx = nx; cy = ny; cz = nz;
    }

    // final fold of remaining stack entries
#pragma unroll
    for (int r = 0; r < 4; ++r) {
        if (cnt[r] > 0)
            rebuild_q(t16_sh[wid][r], stk_sh[wid][r], cnt[r], lane,
                      P, XS[r], A2[r], B2[r], C2[r], true);
    }
    __syncthreads();

    // tail: wave wid merges queries {2*wid, 2*wid+1}; 32-lane half h handles
    // query qq = 2*wid + h, merging the two waves' sorted t16s (bitonic merge).
    {
        const int h   = lane >> 5;
        const int l32 = lane & 31;
        const int qq  = 2 * wid + h;       // 0..7 within block
        const int p   = qq >> 2;           // wave pair
        const int r   = qq & 3;
        unsigned long long v =
            (l32 < 16) ? t16_sh[2 * p][r][l32 & 15]
                       : t16_sh[2 * p + 1][r][(31 - l32) & 15];   // B descending
#pragma unroll
        for (int j = 16; j > 0; j >>= 1) {
            unsigned long long p2 = __shfl_xor(v, j);
            bool keepmin = (l32 & j) == 0;
            bool less = p2 < v;
            v = (keepmin == less) ? p2 : v;
        }
        if (l32 < 16) {
            int idx = (int)(unsigned)v;
            float gx = P[idx];
            float gy = P[MPTS + idx];
            float gz = P[2 * MPTS + idx];
#pragma unroll
            for (int off = 8; off > 0; off >>= 1) {
                gx += __shfl_down(gx, off, 16);
                gy += __shfl_down(gy, off, 16);
                gz += __shfl_down(gz, off, 16);
            }
            if (l32 == 0) {
                int n = QPB * nb + qq;
                n = (n < NQ) ? n : (NQ - 1);  // duplicate writes identical
                float* o = out + n * 15 + 3 + 3 * pc;
                o[0] = gx * 0.0625f;
                o[1] = gy * 0.0625f;
                o[2] = gz * 0.0625f;
            }
        }
    }
}

extern "C" void kernel_launch(void* const* d_in, const int* in_sizes, int n_in,
                              void* d_out, int out_size, void* d_ws, size_t ws_size,
                              hipStream_t stream) {
    const float* inp = (const float*)d_in[0];
    const float* pc0 = (const float*)d_in[1];
    const float* pc1 = (const float*)d_in[2];
    const float* pc2 = (const float*)d_in[3];
    const float* pc3 = (const float*)d_in[4];
    float* out = (float*)d_out;

    hipLaunchKernelGGL(passthrough_kernel, dim3((NQ * 3 + 255) / 256), dim3(256),
                       0, stream, inp, out);

    // 4 pcs x 321 blocks; block = 8 queries, 2 wave-pairs x (2 waves x 8192 pts)
    hipLaunchKernelGGL(knn_kernel, dim3(4 * NBQ), dim3(256), 0, stream,
                       inp, pc0, pc1, pc2, pc3, out);
}